// Round 1
// baseline (478.469 us; speedup 1.0000x reference)
//
#include <hip/hip_runtime.h>
#include <hip/hip_bf16.h>
#include <math.h>

// ---------------- problem constants ----------------
#define L_SEQ 4096            // H*W = 64*64
#define NB    4               // batch
#define DIMC  192
#define DIN   384             // d_inner
#define DIN2  768             // 2*d_inner
#define DTRANK 12
#define DSTATE 16
#define NKX   44              // dt_rank + 2*d_state
#define G_CHUNKS 32
#define T_CHUNK  128          // L_SEQ / G_CHUNKS
#define NCH  (NB*DIN*DSTATE)  // 24576 scan channels

#define NBD ((size_t)NB*DIN*L_SEQ)   // 6,291,456 floats per (B,384,L) buffer

__device__ __forceinline__ float silu_f(float v) {
    return v / (1.f + __expf(-v));
}
__device__ __forceinline__ float softplus_f(float v) {
    return fmaxf(v, 0.f) + log1pf(__expf(-fabsf(v)));
}

// ---------------- generic fp32 tiled GEMM ----------------
// out[j,l] = sum_c W[j*KDIM+c] * X[b][c*L + l],  64x64 tile, 256 thr, 4x4 micro
// rows j < jsplit go to out0 (rows0 rows per batch), else out1 (rows1 per batch).
template<int KDIM>
__launch_bounds__(256)
__global__ void k_gemm(const float* __restrict__ X, const float* __restrict__ W,
                       float* __restrict__ out0, float* __restrict__ out1,
                       int jsplit, int rows0, int rows1) {
    __shared__ __align__(16) float sW[16][68];
    __shared__ __align__(16) float sX[16][68];
    const int b  = blockIdx.z;
    const int j0 = blockIdx.y * 64;
    const int l0 = blockIdx.x * 64;
    const int tid = threadIdx.x;
    const int tx = tid & 15;   // l quad index
    const int ty = tid >> 4;   // j quad index
    float acc[4][4] = {};
    const float* Xb = X + (size_t)b * KDIM * L_SEQ;
    const int wj = tid >> 2;         // 0..63
    const int wc = (tid & 3) * 4;    // 0,4,8,12
    const int xc = tid >> 4;         // 0..15
    const int xl = (tid & 15) * 4;   // 0..60

    for (int c0 = 0; c0 < KDIM; c0 += 16) {
        const float4 w4 = *(const float4*)&W[(size_t)(j0 + wj) * KDIM + c0 + wc];
        const float4 x4 = *(const float4*)&Xb[(size_t)(c0 + xc) * L_SEQ + l0 + xl];
        __syncthreads();
        sW[wc+0][wj] = w4.x; sW[wc+1][wj] = w4.y;
        sW[wc+2][wj] = w4.z; sW[wc+3][wj] = w4.w;
        *(float4*)&sX[xc][xl] = x4;
        __syncthreads();
#pragma unroll
        for (int k = 0; k < 16; ++k) {
            const float4 a4 = *(const float4*)&sW[k][ty*4];
            const float4 b4 = *(const float4*)&sX[k][tx*4];
            acc[0][0] += a4.x*b4.x; acc[0][1] += a4.x*b4.y; acc[0][2] += a4.x*b4.z; acc[0][3] += a4.x*b4.w;
            acc[1][0] += a4.y*b4.x; acc[1][1] += a4.y*b4.y; acc[1][2] += a4.y*b4.z; acc[1][3] += a4.y*b4.w;
            acc[2][0] += a4.z*b4.x; acc[2][1] += a4.z*b4.y; acc[2][2] += a4.z*b4.z; acc[2][3] += a4.z*b4.w;
            acc[3][0] += a4.w*b4.x; acc[3][1] += a4.w*b4.y; acc[3][2] += a4.w*b4.z; acc[3][3] += a4.w*b4.w;
        }
    }
    float* dst;
    if (j0 < jsplit) dst = out0 + ((size_t)b * rows0 + j0) * L_SEQ;
    else             dst = out1 + ((size_t)b * rows1 + (j0 - jsplit)) * L_SEQ;
#pragma unroll
    for (int i = 0; i < 4; ++i) {
        float4 v = make_float4(acc[i][0], acc[i][1], acc[i][2], acc[i][3]);
        *(float4*)&dst[(size_t)(ty*4 + i) * L_SEQ + l0 + tx*4] = v;
    }
}

// ---------------- depthwise causal conv4 + SiLU ----------------
__launch_bounds__(256)
__global__ void k_conv(const float* __restrict__ xin, const float* __restrict__ cw,
                       const float* __restrict__ cb, float* __restrict__ xconv) {
    const int idx = blockIdx.x * 256 + threadIdx.x;   // B*DIN*L threads
    const int l  = idx & (L_SEQ - 1);
    const int bd = idx >> 12;
    const int d  = bd % DIN;
    const float* row = xin + (size_t)bd * L_SEQ;
    float s = cb[d];
#pragma unroll
    for (int k = 0; k < 4; ++k) {
        const int ll = l - 3 + k;
        const float v = (ll >= 0) ? row[ll] : 0.f;
        s += v * cw[d*4 + k];
    }
    xconv[idx] = silu_f(s);
}

// ---------------- x_proj: xdbl[b][l][k] = sum_d xconv[b][d][l]*Wx[k][d] ----------------
__launch_bounds__(256)
__global__ void k_xproj(const float* __restrict__ xconv, const float* __restrict__ Wx,
                        float* __restrict__ xdbl) {
    __shared__ float sw[4][DIN];
    const int tid = threadIdx.x;
    const int b = blockIdx.y;
    const int kk0 = blockIdx.z * 4;
    const int l = blockIdx.x * 256 + tid;
    for (int i = tid; i < 4*DIN; i += 256)
        sw[i / DIN][i % DIN] = Wx[(size_t)(kk0 + i / DIN) * DIN + (i % DIN)];
    __syncthreads();
    const float* xc = xconv + (size_t)b * DIN * L_SEQ + l;
    float a0 = 0.f, a1 = 0.f, a2 = 0.f, a3 = 0.f;
    for (int d = 0; d < DIN; ++d) {
        const float v = xc[(size_t)d * L_SEQ];
        a0 += v * sw[0][d]; a1 += v * sw[1][d];
        a2 += v * sw[2][d]; a3 += v * sw[3][d];
    }
    *(float4*)&xdbl[((size_t)b * L_SEQ + l) * NKX + kk0] = make_float4(a0, a1, a2, a3);
}

// ---------------- dt_proj + double bias + softplus ----------------
__launch_bounds__(64)
__global__ void k_dtproj(const float* __restrict__ xdbl, const float* __restrict__ Wdt,
                         const float* __restrict__ bdt, float* __restrict__ dlt) {
    __shared__ float sx[64][13];
    const int tid = threadIdx.x;          // 64
    const int l0 = blockIdx.x * 64;
    const int d0 = blockIdx.y * 64;
    const int b  = blockIdx.z;
    const float* src = xdbl + ((size_t)b * L_SEQ + l0) * NKX;
    for (int i = tid; i < 64*12; i += 64) {
        const int row = i / 12, r = i % 12;
        sx[row][r] = src[(size_t)row * NKX + r];
    }
    __syncthreads();
    for (int dd = 0; dd < 64; ++dd) {
        const int d = d0 + dd;
        float s = 2.f * bdt[d];
#pragma unroll
        for (int r = 0; r < 12; ++r) s += sx[tid][r] * Wdt[d*12 + r];
        dlt[((size_t)b * DIN + d) * L_SEQ + l0 + tid] = softplus_f(s);
    }
}

// ---------------- scan phase a: per-chunk partial state + chunk product ----------------
__launch_bounds__(256)
__global__ void k_scan_a(const float* __restrict__ dlt, const float* __restrict__ xconv,
                         const float* __restrict__ xdbl, const float* __restrict__ A_log,
                         float* __restrict__ S, float* __restrict__ P) {
    const int tid = threadIdx.x;
    const int n = tid & 15, dloc = tid >> 4;
    const int d = blockIdx.y * 16 + dloc;
    const int g = blockIdx.x;
    const int b = blockIdx.z;
    const float A = -__expf(A_log[d*DSTATE + n]);
    const size_t rowoff = ((size_t)b * DIN + d) * L_SEQ;
    const float* dl = dlt + rowoff;
    const float* ul = xconv + rowoff;
    const float* xb = xdbl + (size_t)b * L_SEQ * NKX + DTRANK + n;
    float h = 0.f, dsum = 0.f;
    const int l0 = g * T_CHUNK;
    for (int t = 0; t < T_CHUNK; ++t) {
        const int l = l0 + t;
        const float dv = dl[l];
        const float uv = ul[l];
        const float Bv = xb[(size_t)l * NKX];
        h = __expf(dv * A) * h + dv * uv * Bv;
        dsum += dv;
    }
    const int ch = (b * DIN + d) * DSTATE + n;
    S[(size_t)g * NCH + ch] = h;
    P[(size_t)g * NCH + ch] = __expf(A * dsum);
}

// ---------------- scan phase b: sequential combine over chunks ----------------
__launch_bounds__(64)
__global__ void k_scan_b(const float* __restrict__ S, const float* __restrict__ P,
                         float* __restrict__ Hst) {
    const int ch = blockIdx.x * 64 + threadIdx.x;
    float h = 0.f;
    for (int g = 0; g < G_CHUNKS; ++g) {
        const size_t i = (size_t)g * NCH + ch;
        Hst[i] = h;                 // state ENTERING chunk g
        h = P[i] * h + S[i];
    }
}

// ---------------- scan phase c: replay with true entering state, y + D*u, gate ----------------
__launch_bounds__(256)
__global__ void k_scan_c(const float* __restrict__ dlt, const float* __restrict__ xconv,
                         const float* __restrict__ xdbl, const float* __restrict__ A_log,
                         const float* __restrict__ Hst, const float* __restrict__ zg,
                         const float* __restrict__ Dv, float* __restrict__ yg) {
    const int tid = threadIdx.x;
    const int n = tid & 15, dloc = tid >> 4;
    const int d = blockIdx.y * 16 + dloc;
    const int g = blockIdx.x;
    const int b = blockIdx.z;
    const float A = -__expf(A_log[d*DSTATE + n]);
    const size_t rowoff = ((size_t)b * DIN + d) * L_SEQ;
    const float* dl = dlt + rowoff;
    const float* ul = xconv + rowoff;
    const float* zl = zg + rowoff;
    float* yl = yg + rowoff;
    const float* xbB = xdbl + (size_t)b * L_SEQ * NKX + DTRANK + n;
    const float* xbC = xdbl + (size_t)b * L_SEQ * NKX + DTRANK + DSTATE + n;
    const int ch = (b * DIN + d) * DSTATE + n;
    float h = Hst[(size_t)g * NCH + ch];
    const float Dd = Dv[d];
    const int l0 = g * T_CHUNK;
    for (int t = 0; t < T_CHUNK; ++t) {
        const int l = l0 + t;
        const float dv = dl[l];
        const float uv = ul[l];
        const float Bv = xbB[(size_t)l * NKX];
        const float Cv = xbC[(size_t)l * NKX];
        h = __expf(dv * A) * h + dv * uv * Bv;
        float y = h * Cv;
        y += __shfl_xor(y, 1);
        y += __shfl_xor(y, 2);
        y += __shfl_xor(y, 4);
        y += __shfl_xor(y, 8);
        if (n == 0) {
            const float zz = zl[l];
            yl[l] = (y + Dd * uv) * silu_f(zz);
        }
    }
}

// ---------------- launcher ----------------
extern "C" void kernel_launch(void* const* d_in, const int* in_sizes, int n_in,
                              void* d_out, int out_size, void* d_ws, size_t ws_size,
                              hipStream_t stream) {
    const float* x      = (const float*)d_in[0];
    const float* W_in   = (const float*)d_in[1];
    const float* conv_w = (const float*)d_in[2];
    const float* conv_b = (const float*)d_in[3];
    const float* W_x    = (const float*)d_in[4];
    const float* W_dt   = (const float*)d_in[5];
    const float* b_dt   = (const float*)d_in[6];
    const float* A_log  = (const float*)d_in[7];
    const float* Dvec   = (const float*)d_in[8];
    const float* W_out  = (const float*)d_in[9];
    float* out = (float*)d_out;

    float* ws    = (float*)d_ws;
    float* xin   = ws;                       // (B,384,L)
    float* zg    = xin   + NBD;              // (B,384,L)
    float* xconv = zg    + NBD;              // (B,384,L)
    float* dlt   = xconv + NBD;              // (B,384,L)
    float* xdbl  = dlt   + NBD;              // (B,L,44)
    float* S     = xdbl  + (size_t)NB*L_SEQ*NKX;   // (G,NCH)
    float* P     = S     + (size_t)G_CHUNKS*NCH;
    float* Hst   = P     + (size_t)G_CHUNKS*NCH;
    float* ygate = xin;                      // reuse xin (dead after conv)

    // 1. in_proj: (768x192) @ (192xL) per batch -> xin (j<384), zg (j>=384)
    k_gemm<DIMC><<<dim3(L_SEQ/64, DIN2/64, NB), 256, 0, stream>>>(
        x, W_in, xin, zg, DIN, DIN, DIN);
    // 2. depthwise causal conv + silu
    k_conv<<<dim3((NB*DIN*L_SEQ)/256), 256, 0, stream>>>(xin, conv_w, conv_b, xconv);
    // 3. x_proj -> xdbl (B,L,44)
    k_xproj<<<dim3(L_SEQ/256, NB, NKX/4), 256, 0, stream>>>(xconv, W_x, xdbl);
    // 4. dt_proj + softplus -> dlt (B,384,L)
    k_dtproj<<<dim3(L_SEQ/64, DIN/64, NB), 64, 0, stream>>>(xdbl, W_dt, b_dt, dlt);
    // 5. chunked selective scan
    k_scan_a<<<dim3(G_CHUNKS, DIN/16, NB), 256, 0, stream>>>(dlt, xconv, xdbl, A_log, S, P);
    k_scan_b<<<dim3(NCH/64), 64, 0, stream>>>(S, P, Hst);
    k_scan_c<<<dim3(G_CHUNKS, DIN/16, NB), 256, 0, stream>>>(dlt, xconv, xdbl, A_log,
                                                             Hst, zg, Dvec, ygate);
    // 6. out_proj: (192x384) @ (384xL) per batch -> out
    k_gemm<DIN><<<dim3(L_SEQ/64, DIMC/64, NB), 256, 0, stream>>>(
        ygate, W_out, out, out, DIMC, DIMC, DIMC);
}

// Round 2
// 358.887 us; speedup vs baseline: 1.3332x; 1.3332x over previous
//
#include <hip/hip_runtime.h>
#include <hip/hip_bf16.h>
#include <math.h>

// ---------------- problem constants ----------------
#define L_SEQ 4096            // H*W
#define NB    4
#define DIMC  192
#define DIN   384             // d_inner
#define DIN2  768
#define DTRANK 12
#define DSTATE 16
#define NKX   44              // dt_rank + 2*d_state
#define G_CHUNKS 64
#define T_CHUNK  64           // L_SEQ / G_CHUNKS
#define NCH  (NB*DIN*DSTATE)  // 24576 scan channels
#define NM   (NB*L_SEQ)       // 16384 (b,l) rows

__device__ __forceinline__ float silu_f(float v) {
    return v / (1.f + __expf(-v));
}
__device__ __forceinline__ float softplus_f(float v) {
    return fmaxf(v, 0.f) + log1pf(__expf(-fabsf(v)));
}

// ---------------- in_proj GEMM: out(b,l,j) = sum_c X[b][c][l] * W[j][c] ----------------
// j < 384 -> out0 (b,l,384);  j >= 384 -> out1 (b,l,384)
__launch_bounds__(256)
__global__ void k_gemm_in(const float* __restrict__ X, const float* __restrict__ W,
                          float* __restrict__ out0, float* __restrict__ out1) {
    __shared__ __align__(16) float sX[16][68];   // [c][l]
    __shared__ __align__(16) float sW[16][68];   // [c][j]
    const int b  = blockIdx.z;
    const int l0 = blockIdx.x * 64;
    const int j0 = blockIdx.y * 64;
    const int tid = threadIdx.x;
    const int tx = tid & 15;    // j quad
    const int ty = tid >> 4;    // l quad
    float acc[4][4] = {};
    const float* Xb = X + (size_t)b * DIMC * L_SEQ;
    const int xc = tid >> 4, xl = (tid & 15) * 4;
    const int wj = tid >> 2, wc = (tid & 3) * 4;
    for (int c0 = 0; c0 < DIMC; c0 += 16) {
        const float4 x4 = *(const float4*)&Xb[(size_t)(c0 + xc) * L_SEQ + l0 + xl];
        const float4 w4 = *(const float4*)&W[(size_t)(j0 + wj) * DIMC + c0 + wc];
        __syncthreads();
        *(float4*)&sX[xc][xl] = x4;
        sW[wc+0][wj] = w4.x; sW[wc+1][wj] = w4.y;
        sW[wc+2][wj] = w4.z; sW[wc+3][wj] = w4.w;
        __syncthreads();
#pragma unroll
        for (int k = 0; k < 16; ++k) {
            const float4 a4 = *(const float4*)&sX[k][ty*4];
            const float4 b4 = *(const float4*)&sW[k][tx*4];
            acc[0][0] += a4.x*b4.x; acc[0][1] += a4.x*b4.y; acc[0][2] += a4.x*b4.z; acc[0][3] += a4.x*b4.w;
            acc[1][0] += a4.y*b4.x; acc[1][1] += a4.y*b4.y; acc[1][2] += a4.y*b4.z; acc[1][3] += a4.y*b4.w;
            acc[2][0] += a4.z*b4.x; acc[2][1] += a4.z*b4.y; acc[2][2] += a4.z*b4.z; acc[2][3] += a4.z*b4.w;
            acc[3][0] += a4.w*b4.x; acc[3][1] += a4.w*b4.y; acc[3][2] += a4.w*b4.z; acc[3][3] += a4.w*b4.w;
        }
    }
    float* dst; int jo;
    if (j0 < DIN) { dst = out0; jo = j0; } else { dst = out1; jo = j0 - DIN; }
    dst += (size_t)b * L_SEQ * DIN;
#pragma unroll
    for (int i = 0; i < 4; ++i) {
        float4 v = make_float4(acc[i][0], acc[i][1], acc[i][2], acc[i][3]);
        *(float4*)&dst[(size_t)(l0 + ty*4 + i) * DIN + jo + tx*4] = v;
    }
}

// ---------------- NT GEMM: C[m][n] = sum_k A[m][k]*B[n][k], A/B row-major K-inner ----
// OUTMODE 0: C row-major (ldc), guard n < nvalid      (x_proj)
// OUTMODE 1: C is (b, DIMC, L): n = b*L + l            (out_proj)
template<int OUTMODE>
__launch_bounds__(256)
__global__ void k_gemm_nt(const float* __restrict__ A, const float* __restrict__ Bm,
                          float* __restrict__ C, int Krun, int lda, int ldb,
                          int ldc, int nvalid) {
    __shared__ __align__(16) float sA[16][68];   // [k][m]
    __shared__ __align__(16) float sB[16][68];   // [k][n]
    const int m0 = blockIdx.x * 64;
    const int n0 = blockIdx.y * 64;
    const int tid = threadIdx.x;
    const int tx = tid & 15;    // n quad
    const int ty = tid >> 4;    // m quad
    float acc[4][4] = {};
    const int lr = tid >> 2, kq = (tid & 3) * 4;
    for (int k0 = 0; k0 < Krun; k0 += 16) {
        const float4 a4 = *(const float4*)&A[(size_t)(m0 + lr) * lda + k0 + kq];
        float4 b4 = make_float4(0.f, 0.f, 0.f, 0.f);
        if (n0 + lr < nvalid)
            b4 = *(const float4*)&Bm[(size_t)(n0 + lr) * ldb + k0 + kq];
        __syncthreads();
        sA[kq+0][lr] = a4.x; sA[kq+1][lr] = a4.y; sA[kq+2][lr] = a4.z; sA[kq+3][lr] = a4.w;
        sB[kq+0][lr] = b4.x; sB[kq+1][lr] = b4.y; sB[kq+2][lr] = b4.z; sB[kq+3][lr] = b4.w;
        __syncthreads();
#pragma unroll
        for (int k = 0; k < 16; ++k) {
            const float4 a4i = *(const float4*)&sA[k][ty*4];
            const float4 b4i = *(const float4*)&sB[k][tx*4];
            acc[0][0] += a4i.x*b4i.x; acc[0][1] += a4i.x*b4i.y; acc[0][2] += a4i.x*b4i.z; acc[0][3] += a4i.x*b4i.w;
            acc[1][0] += a4i.y*b4i.x; acc[1][1] += a4i.y*b4i.y; acc[1][2] += a4i.y*b4i.z; acc[1][3] += a4i.y*b4i.w;
            acc[2][0] += a4i.z*b4i.x; acc[2][1] += a4i.z*b4i.y; acc[2][2] += a4i.z*b4i.z; acc[2][3] += a4i.z*b4i.w;
            acc[3][0] += a4i.w*b4i.x; acc[3][1] += a4i.w*b4i.y; acc[3][2] += a4i.w*b4i.z; acc[3][3] += a4i.w*b4i.w;
        }
    }
    const int ncol = n0 + tx*4;
    if (OUTMODE == 0) {
        if (ncol < nvalid) {
#pragma unroll
            for (int i = 0; i < 4; ++i) {
                float4 v = make_float4(acc[i][0], acc[i][1], acc[i][2], acc[i][3]);
                *(float4*)&C[(size_t)(m0 + ty*4 + i) * ldc + ncol] = v;
            }
        }
    } else {
        const int bb = ncol >> 12;            // n = b*L + l
        const int ll = ncol & (L_SEQ - 1);
        float* dst = C + (size_t)bb * DIMC * L_SEQ + ll;
#pragma unroll
        for (int i = 0; i < 4; ++i) {
            float4 v = make_float4(acc[i][0], acc[i][1], acc[i][2], acc[i][3]);
            *(float4*)&dst[(size_t)(m0 + ty*4 + i) * L_SEQ] = v;
        }
    }
}

// ---------------- depthwise causal conv4 + SiLU, (b,l,d) layout ----------------
__launch_bounds__(256)
__global__ void k_conv(const float* __restrict__ xin, const float* __restrict__ cw,
                       const float* __restrict__ cb, float* __restrict__ xconv) {
    const int idx = blockIdx.x * 256 + threadIdx.x;   // (b*L + l)*DIN + d
    const int d = idx % DIN;
    const int m = idx / DIN;
    const int l = m & (L_SEQ - 1);
    const float4 w4 = *(const float4*)&cw[d * 4];
    float s = cb[d];
    const float w[4] = {w4.x, w4.y, w4.z, w4.w};
#pragma unroll
    for (int k = 0; k < 4; ++k) {
        const int ll = l - 3 + k;
        if (ll >= 0) s += xin[(size_t)(m - 3 + k) * DIN + d] * w[k];
    }
    xconv[idx] = silu_f(s);
}

// ---------------- dt_proj + double bias + softplus, (b,l,d) ----------------
__launch_bounds__(384)
__global__ void k_dtproj(const float* __restrict__ xdbl, const float* __restrict__ Wdt,
                         const float* __restrict__ bdt, float* __restrict__ dlt) {
    __shared__ float sx[8][12];
    const int tid = threadIdx.x;          // d
    const int b  = blockIdx.y;
    const int l0 = blockIdx.x * 8;
    const size_t row0 = (size_t)b * L_SEQ + l0;
    if (tid < 96) sx[tid / 12][tid % 12] = xdbl[(row0 + tid / 12) * NKX + (tid % 12)];
    __syncthreads();
    const int d = tid;
    float w[12];
#pragma unroll
    for (int r = 0; r < 12; ++r) w[r] = Wdt[d * 12 + r];
    const float bb = 2.f * bdt[d];
#pragma unroll
    for (int i = 0; i < 8; ++i) {
        float s = bb;
#pragma unroll
        for (int r = 0; r < 12; ++r) s += sx[i][r] * w[r];
        dlt[(row0 + i) * DIN + d] = softplus_f(s);
    }
}

// ---------------- scan phase a: per-chunk partial state + chunk product --------
// thread owns d; h[16] in registers; B from LDS broadcast
__launch_bounds__(384)
__global__ void k_scan_a(const float* __restrict__ dlt, const float* __restrict__ xconv,
                         const float* __restrict__ xdbl, const float* __restrict__ A_log,
                         float* __restrict__ S, float* __restrict__ P) {
    __shared__ __align__(16) float sBC[T_CHUNK][32];
    const int tid = threadIdx.x;
    const int g = blockIdx.x, b = blockIdx.y;
    const int l0 = g * T_CHUNK;
    const size_t row0 = (size_t)b * L_SEQ + l0;
    for (int i = tid; i < T_CHUNK * 8; i += 384) {
        const int l = i >> 3, q = (i & 7) * 4;
        *(float4*)&sBC[l][q] = *(const float4*)&xdbl[(row0 + l) * NKX + DTRANK + q];
    }
    __syncthreads();
    const int d = tid;
    float A[DSTATE];
#pragma unroll
    for (int n = 0; n < DSTATE; ++n) A[n] = -__expf(A_log[d * DSTATE + n]);
    float h[DSTATE] = {};
    float dsum = 0.f;
    const float* dl = dlt + row0 * DIN + d;
    const float* ul = xconv + row0 * DIN + d;
    for (int t = 0; t < T_CHUNK; ++t) {
        const float dv = dl[(size_t)t * DIN];
        const float uv = ul[(size_t)t * DIN];
        const float dub = dv * uv;
        dsum += dv;
#pragma unroll
        for (int n = 0; n < DSTATE; ++n) {
            const float e = __expf(dv * A[n]);
            h[n] = e * h[n] + dub * sBC[t][n];
        }
    }
    float* Sp = S + (size_t)g * NCH + (size_t)(b * DIN + d) * DSTATE;
    float* Pp = P + (size_t)g * NCH + (size_t)(b * DIN + d) * DSTATE;
#pragma unroll
    for (int n = 0; n < DSTATE; n += 4) {
        *(float4*)&Sp[n] = make_float4(h[n], h[n+1], h[n+2], h[n+3]);
        *(float4*)&Pp[n] = make_float4(__expf(A[n]*dsum), __expf(A[n+1]*dsum),
                                       __expf(A[n+2]*dsum), __expf(A[n+3]*dsum));
    }
}

// ---------------- scan phase b: sequential combine; writes entering state into S --
__launch_bounds__(256)
__global__ void k_scan_b(float* __restrict__ Sh, const float* __restrict__ P) {
    const int ch = blockIdx.x * 256 + threadIdx.x;
    float h = 0.f;
    for (int g = 0; g < G_CHUNKS; ++g) {
        const size_t i = (size_t)g * NCH + ch;
        const float s = Sh[i];
        const float p = P[i];
        Sh[i] = h;                 // state ENTERING chunk g
        h = p * h + s;
    }
}

// ---------------- scan phase c: replay + y + D*u + gate, all coalesced ----------
__launch_bounds__(384)
__global__ void k_scan_c(const float* __restrict__ dlt, const float* __restrict__ xconv,
                         const float* __restrict__ xdbl, const float* __restrict__ A_log,
                         const float* __restrict__ Hst, const float* __restrict__ zg,
                         const float* __restrict__ Dv, float* __restrict__ yg) {
    __shared__ __align__(16) float sBC[T_CHUNK][32];
    const int tid = threadIdx.x;
    const int g = blockIdx.x, b = blockIdx.y;
    const int l0 = g * T_CHUNK;
    const size_t row0 = (size_t)b * L_SEQ + l0;
    for (int i = tid; i < T_CHUNK * 8; i += 384) {
        const int l = i >> 3, q = (i & 7) * 4;
        *(float4*)&sBC[l][q] = *(const float4*)&xdbl[(row0 + l) * NKX + DTRANK + q];
    }
    __syncthreads();
    const int d = tid;
    float A[DSTATE];
#pragma unroll
    for (int n = 0; n < DSTATE; ++n) A[n] = -__expf(A_log[d * DSTATE + n]);
    float h[DSTATE];
    const float* Hp = Hst + (size_t)g * NCH + (size_t)(b * DIN + d) * DSTATE;
#pragma unroll
    for (int n = 0; n < DSTATE; n += 4) {
        const float4 h4 = *(const float4*)&Hp[n];
        h[n] = h4.x; h[n+1] = h4.y; h[n+2] = h4.z; h[n+3] = h4.w;
    }
    const float Dd = Dv[d];
    const float* dl = dlt + row0 * DIN + d;
    const float* ul = xconv + row0 * DIN + d;
    const float* zl = zg + row0 * DIN + d;
    float* yl = yg + row0 * DIN + d;
    for (int t = 0; t < T_CHUNK; ++t) {
        const float dv = dl[(size_t)t * DIN];
        const float uv = ul[(size_t)t * DIN];
        const float zz = zl[(size_t)t * DIN];
        const float dub = dv * uv;
        float y0 = 0.f, y1 = 0.f, y2 = 0.f, y3 = 0.f;
#pragma unroll
        for (int n = 0; n < DSTATE; n += 4) {
            float e;
            e = __expf(dv * A[n  ]); h[n  ] = e * h[n  ] + dub * sBC[t][n  ]; y0 += h[n  ] * sBC[t][16+n  ];
            e = __expf(dv * A[n+1]); h[n+1] = e * h[n+1] + dub * sBC[t][n+1]; y1 += h[n+1] * sBC[t][16+n+1];
            e = __expf(dv * A[n+2]); h[n+2] = e * h[n+2] + dub * sBC[t][n+2]; y2 += h[n+2] * sBC[t][16+n+2];
            e = __expf(dv * A[n+3]); h[n+3] = e * h[n+3] + dub * sBC[t][n+3]; y3 += h[n+3] * sBC[t][16+n+3];
        }
        const float y = (y0 + y1) + (y2 + y3);
        yl[(size_t)t * DIN] = (y + Dd * uv) * silu_f(zz);
    }
}

// ---------------- launcher ----------------
extern "C" void kernel_launch(void* const* d_in, const int* in_sizes, int n_in,
                              void* d_out, int out_size, void* d_ws, size_t ws_size,
                              hipStream_t stream) {
    const float* x      = (const float*)d_in[0];
    const float* W_in   = (const float*)d_in[1];
    const float* conv_w = (const float*)d_in[2];
    const float* conv_b = (const float*)d_in[3];
    const float* W_x    = (const float*)d_in[4];
    const float* W_dt   = (const float*)d_in[5];
    const float* b_dt   = (const float*)d_in[6];
    const float* A_log  = (const float*)d_in[7];
    const float* Dvec   = (const float*)d_in[8];
    const float* W_out  = (const float*)d_in[9];
    float* out = (float*)d_out;

    float* ws    = (float*)d_ws;
    float* xin   = ws;                           // (b,l,384)
    float* zg    = xin   + (size_t)NM * DIN;     // (b,l,384)
    float* xconv = zg    + (size_t)NM * DIN;     // (b,l,384)
    float* dlt   = xconv + (size_t)NM * DIN;     // (b,l,384)
    float* xdbl  = dlt   + (size_t)NM * DIN;     // (b*l, 44)
    float* S     = xdbl  + (size_t)NM * NKX;     // (G, NCH); becomes Hst after phase b
    float* P     = S     + (size_t)G_CHUNKS * NCH;
    float* yg    = xin;                          // reuse (dead after conv)

    // 1. in_proj -> xin (b,l,384) + zg (b,l,384)
    k_gemm_in<<<dim3(L_SEQ/64, DIN2/64, NB), 256, 0, stream>>>(x, W_in, xin, zg);
    // 2. depthwise causal conv + silu
    k_conv<<<dim3((NM*(size_t)DIN)/256), 256, 0, stream>>>(xin, conv_w, conv_b, xconv);
    // 3. x_proj: xdbl(b*l,44) = xconv(b*l,384) @ W_x^T
    k_gemm_nt<0><<<dim3(NM/64, 1), 256, 0, stream>>>(xconv, W_x, xdbl, DIN, DIN, DIN, NKX, NKX);
    // 4. dt_proj + softplus -> dlt (b,l,384)
    k_dtproj<<<dim3(L_SEQ/8, NB), 384, 0, stream>>>(xdbl, W_dt, b_dt, dlt);
    // 5. chunked selective scan
    k_scan_a<<<dim3(G_CHUNKS, NB), 384, 0, stream>>>(dlt, xconv, xdbl, A_log, S, P);
    k_scan_b<<<dim3(NCH/256), 256, 0, stream>>>(S, P);
    k_scan_c<<<dim3(G_CHUNKS, NB), 384, 0, stream>>>(dlt, xconv, xdbl, A_log, S, zg, Dvec, yg);
    // 6. out_proj: out(b,192,l) = W_out(192,384) @ yg(b*l,384)^T
    k_gemm_nt<1><<<dim3(DIMC/64, NM/64), 256, 0, stream>>>(W_out, yg, out, DIN, DIN, DIN, 0, 1<<30);
}

// Round 3
// 291.383 us; speedup vs baseline: 1.6421x; 1.2317x over previous
//
#include <hip/hip_runtime.h>
#include <hip/hip_bf16.h>
#include <math.h>

// ---------------- problem constants ----------------
#define L_SEQ 4096            // H*W
#define NB    4
#define DIMC  192
#define DIN   384             // d_inner
#define DIN2  768
#define DTRANK 12
#define DSTATE 16
#define NKX   44              // dt_rank + 2*d_state
#define G_CHUNKS 64
#define T_CHUNK  64           // L_SEQ / G_CHUNKS
#define NCH  (NB*DIN*DSTATE)  // 24576 scan channels
#define NM   (NB*L_SEQ)       // 16384 (b,l) rows

typedef __attribute__((ext_vector_type(8))) short short8;     // 8 bf16 = 4 VGPRs
typedef __attribute__((ext_vector_type(4))) float floatx4;

__device__ __forceinline__ float silu_f(float v) {
    return v / (1.f + __expf(-v));
}
__device__ __forceinline__ float softplus_f(float v) {
    return fmaxf(v, 0.f) + log1pf(__expf(-fabsf(v)));
}

// async global->LDS 16B per lane (wave-uniform base + lane*16 layout)
#define GLOAD_LDS16(g, l)                                                       \
    __builtin_amdgcn_global_load_lds(                                           \
        (const __attribute__((address_space(1))) unsigned int*)(uintptr_t)(g),  \
        (__attribute__((address_space(3))) unsigned int*)(unsigned int)(uintptr_t)(l), \
        16, 0, 0)

// ---------------- convert + transpose x: (b,c,l) f32 -> (b*l, c) bf16 ----------------
__launch_bounds__(256)
__global__ void k_cvt_x(const float* __restrict__ x, __hip_bfloat16* __restrict__ xb) {
    __shared__ float s[32][33];
    const int b = blockIdx.z, c0 = blockIdx.y * 32, l0 = blockIdx.x * 32;
    const int tx = threadIdx.x, ty = threadIdx.y;   // (32, 8)
    const float* xp = x + ((size_t)b * DIMC + c0) * L_SEQ + l0;
#pragma unroll
    for (int r = 0; r < 4; ++r)
        s[ty + r*8][tx] = xp[(size_t)(ty + r*8) * L_SEQ + tx];
    __syncthreads();
    __hip_bfloat16* op = xb + ((size_t)b * L_SEQ + l0) * DIMC + c0;
#pragma unroll
    for (int r = 0; r < 4; ++r) {
        const int lr = ty + r*8;
        op[(size_t)lr * DIMC + tx] = __float2bfloat16(s[tx][lr]);
    }
}

// ---------------- convert weights to bf16 (W_x zero-padded to 64 rows) -------------
#define NWI (DIN2*DIMC)        // 147456
#define NWO (DIMC*DIN)         // 73728
#define NWX (64*DIN)           // 24576 padded
__launch_bounds__(256)
__global__ void k_cvt_w(const float* __restrict__ W_in, const float* __restrict__ W_out,
                        const float* __restrict__ W_x,
                        __hip_bfloat16* __restrict__ wbi, __hip_bfloat16* __restrict__ wbo,
                        __hip_bfloat16* __restrict__ wbx) {
    const int i = blockIdx.x * 256 + threadIdx.x;
    if (i < NWI) {
        wbi[i] = __float2bfloat16(W_in[i]);
    } else if (i < NWI + NWO) {
        const int j = i - NWI;
        wbo[j] = __float2bfloat16(W_out[j]);
    } else if (i < NWI + NWO + NWX) {
        const int j = i - NWI - NWO;
        const int r = j / DIN, c = j - r * DIN;
        wbx[j] = (r < NKX) ? __float2bfloat16(W_x[r * DIN + c]) : __float2bfloat16(0.f);
    }
}

// ---------------- bf16 NT MFMA GEMM ----------------
// C[m][n] = sum_k A[m][k] * B[n][k];  A: (16384 x K) bf16, B: (N x K) bf16.
// BM=128 fixed; BN in {64,128}. 256 threads = 4 waves in 2x2; wave tile 64 x BN/2.
// OUTMODE 0: C f32 row-major ldc (in_proj -> xz)
// OUTMODE 1: C f32 at out[b][n][l], m = b*4096+l (out_proj)
// OUTMODE 2: C f32 row-major ldc=NKX with n<NKX guard (x_proj)
template<int BN, int OUTMODE>
__launch_bounds__(256)
__global__ void k_mfma(const __hip_bfloat16* __restrict__ A,
                       const __hip_bfloat16* __restrict__ B,
                       float* __restrict__ C, int K, int ldc) {
    constexpr int WN = BN / 2;     // wave n extent
    constexpr int TN = WN / 16;    // n tiles per wave (2 or 4)
    constexpr int RB = BN / 64;    // B staging rounds (1 or 2)
    __shared__ __align__(16) __hip_bfloat16 sAB[(128 + BN) * 32];
    __hip_bfloat16* sA = sAB;
    __hip_bfloat16* sB = sAB + 128 * 32;

    const int tid = threadIdx.x;
    const int lane = tid & 63;
    const int wave = tid >> 6;
    const int wm = wave >> 1, wn = wave & 1;
    const int m0 = blockIdx.x * 128;
    const int n0 = blockIdx.y * BN;
    const int mlan = lane & 15;
    const int kq = (lane >> 4) * 8;

    const int srow = tid >> 2;              // staging row within round
    const int scol = (tid & 3) * 8;         // bf16 col within 32-wide K slab

    floatx4 acc[4][TN];
#pragma unroll
    for (int i = 0; i < 4; ++i)
#pragma unroll
        for (int j = 0; j < TN; ++j) acc[i][j] = (floatx4){0.f, 0.f, 0.f, 0.f};

    for (int k0 = 0; k0 < K; k0 += 32) {
        __syncthreads();
        // stage A tile: 128 x 32 bf16, two rounds of 256 lanes x 16B
#pragma unroll
        for (int r = 0; r < 2; ++r)
            GLOAD_LDS16(&A[(size_t)(m0 + r*64 + srow) * K + k0 + scol],
                        &sA[(size_t)(r*64 + srow) * 32 + scol]);
        // stage B tile: BN x 32 bf16
#pragma unroll
        for (int r = 0; r < RB; ++r)
            GLOAD_LDS16(&B[(size_t)(n0 + r*64 + srow) * K + k0 + scol],
                        &sB[(size_t)(r*64 + srow) * 32 + scol]);
        __syncthreads();

        short8 af[4], bf[TN];
#pragma unroll
        for (int i = 0; i < 4; ++i)
            af[i] = *(const short8*)&sA[(size_t)(wm*64 + i*16 + mlan) * 32 + kq];
#pragma unroll
        for (int j = 0; j < TN; ++j)
            bf[j] = *(const short8*)&sB[(size_t)(wn*WN + j*16 + mlan) * 32 + kq];
#pragma unroll
        for (int i = 0; i < 4; ++i)
#pragma unroll
            for (int j = 0; j < TN; ++j)
                acc[i][j] = __builtin_amdgcn_mfma_f32_16x16x32_bf16(
                    af[i], bf[j], acc[i][j], 0, 0, 0);
    }

    const int quad = lane >> 4;
#pragma unroll
    for (int i = 0; i < 4; ++i) {
#pragma unroll
        for (int j = 0; j < TN; ++j) {
            const int n = n0 + wn*WN + j*16 + mlan;
            const int mb = m0 + wm*64 + i*16 + quad*4;
#pragma unroll
            for (int r = 0; r < 4; ++r) {
                const int m = mb + r;
                const float v = acc[i][j][r];
                if (OUTMODE == 0) {
                    C[(size_t)m * ldc + n] = v;
                } else if (OUTMODE == 1) {
                    const int bb = m >> 12, ll = m & (L_SEQ - 1);
                    C[((size_t)bb * DIMC + n) * L_SEQ + ll] = v;
                } else {
                    if (n < NKX) C[(size_t)m * NKX + n] = v;
                }
            }
        }
    }
}

// ---------------- depthwise causal conv4 + SiLU: xz f32 (stride 768) -> bf16 -------
__launch_bounds__(256)
__global__ void k_conv(const float* __restrict__ xz, const float* __restrict__ cw,
                       const float* __restrict__ cb, __hip_bfloat16* __restrict__ xcb) {
    const int idx = blockIdx.x * 256 + threadIdx.x;   // m*DIN + d
    const int d = idx % DIN;
    const int m = idx / DIN;
    const int l = m & (L_SEQ - 1);
    const float4 w4 = *(const float4*)&cw[d * 4];
    float s = cb[d];
    const float w[4] = {w4.x, w4.y, w4.z, w4.w};
#pragma unroll
    for (int k = 0; k < 4; ++k) {
        const int ll = l - 3 + k;
        if (ll >= 0) s += xz[(size_t)(m - 3 + k) * DIN2 + d] * w[k];
    }
    xcb[idx] = __float2bfloat16(silu_f(s));
}

// ---------------- scan phase a (inline dt_proj): per-chunk state + product --------
__launch_bounds__(384)
__global__ void k_scan_a(const __hip_bfloat16* __restrict__ xcb,
                         const float* __restrict__ xdbl, const float* __restrict__ Wdt,
                         const float* __restrict__ bdt, const float* __restrict__ A_log,
                         float* __restrict__ S, float* __restrict__ P) {
    __shared__ float sX[T_CHUNK * NKX];
    const int tid = threadIdx.x;
    const int g = blockIdx.x, b = blockIdx.y;
    const size_t row0 = (size_t)b * L_SEQ + g * T_CHUNK;
    for (int i = tid; i < T_CHUNK * NKX; i += 384)
        sX[i] = xdbl[row0 * NKX + i];
    __syncthreads();
    const int d = tid;
    float w[DTRANK];
#pragma unroll
    for (int r = 0; r < DTRANK; ++r) w[r] = Wdt[d * DTRANK + r];
    const float bb2 = 2.f * bdt[d];
    float A[DSTATE];
#pragma unroll
    for (int n = 0; n < DSTATE; ++n) A[n] = -__expf(A_log[d * DSTATE + n]);
    float h[DSTATE] = {};
    float dsum = 0.f;
    const __hip_bfloat16* ul = xcb + row0 * DIN + d;
    for (int t = 0; t < T_CHUNK; ++t) {
        float dv = bb2;
#pragma unroll
        for (int r = 0; r < DTRANK; ++r) dv += sX[t*NKX + r] * w[r];
        dv = softplus_f(dv);
        const float uv = __bfloat162float(ul[(size_t)t * DIN]);
        const float dub = dv * uv;
        dsum += dv;
#pragma unroll
        for (int n = 0; n < DSTATE; ++n) {
            const float e = __expf(dv * A[n]);
            h[n] = e * h[n] + dub * sX[t*NKX + DTRANK + n];
        }
    }
    float* Sp = S + (size_t)g * NCH + (size_t)(b * DIN + d) * DSTATE;
    float* Pp = P + (size_t)g * NCH + (size_t)(b * DIN + d) * DSTATE;
#pragma unroll
    for (int n = 0; n < DSTATE; n += 4) {
        *(float4*)&Sp[n] = make_float4(h[n], h[n+1], h[n+2], h[n+3]);
        *(float4*)&Pp[n] = make_float4(__expf(A[n]*dsum), __expf(A[n+1]*dsum),
                                       __expf(A[n+2]*dsum), __expf(A[n+3]*dsum));
    }
}

// ---------------- scan phase b: sequential combine; S becomes entering state ------
__launch_bounds__(256)
__global__ void k_scan_b(float* __restrict__ Sh, const float* __restrict__ P) {
    const int ch = blockIdx.x * 256 + threadIdx.x;
    float h = 0.f;
    for (int g = 0; g < G_CHUNKS; ++g) {
        const size_t i = (size_t)g * NCH + ch;
        const float s = Sh[i];
        const float p = P[i];
        Sh[i] = h;
        h = p * h + s;
    }
}

// ---------------- scan phase c: replay + y + D*u + gate -> yb bf16 ----------------
__launch_bounds__(384)
__global__ void k_scan_c(const __hip_bfloat16* __restrict__ xcb,
                         const float* __restrict__ xdbl, const float* __restrict__ Wdt,
                         const float* __restrict__ bdt, const float* __restrict__ A_log,
                         const float* __restrict__ Hst, const float* __restrict__ xz,
                         const float* __restrict__ Dv, __hip_bfloat16* __restrict__ yb) {
    __shared__ float sX[T_CHUNK * NKX];
    const int tid = threadIdx.x;
    const int g = blockIdx.x, b = blockIdx.y;
    const size_t row0 = (size_t)b * L_SEQ + g * T_CHUNK;
    for (int i = tid; i < T_CHUNK * NKX; i += 384)
        sX[i] = xdbl[row0 * NKX + i];
    __syncthreads();
    const int d = tid;
    float w[DTRANK];
#pragma unroll
    for (int r = 0; r < DTRANK; ++r) w[r] = Wdt[d * DTRANK + r];
    const float bb2 = 2.f * bdt[d];
    float A[DSTATE];
#pragma unroll
    for (int n = 0; n < DSTATE; ++n) A[n] = -__expf(A_log[d * DSTATE + n]);
    float h[DSTATE];
    const float* Hp = Hst + (size_t)g * NCH + (size_t)(b * DIN + d) * DSTATE;
#pragma unroll
    for (int n = 0; n < DSTATE; n += 4) {
        const float4 h4 = *(const float4*)&Hp[n];
        h[n] = h4.x; h[n+1] = h4.y; h[n+2] = h4.z; h[n+3] = h4.w;
    }
    const float Dd = Dv[d];
    const __hip_bfloat16* ul = xcb + row0 * DIN + d;
    const float* zl = xz + row0 * DIN2 + DIN + d;
    __hip_bfloat16* yl = yb + row0 * DIN + d;
    for (int t = 0; t < T_CHUNK; ++t) {
        float dv = bb2;
#pragma unroll
        for (int r = 0; r < DTRANK; ++r) dv += sX[t*NKX + r] * w[r];
        dv = softplus_f(dv);
        const float uv = __bfloat162float(ul[(size_t)t * DIN]);
        const float zz = zl[(size_t)t * DIN2];
        const float dub = dv * uv;
        float y0 = 0.f, y1 = 0.f, y2 = 0.f, y3 = 0.f;
#pragma unroll
        for (int n = 0; n < DSTATE; n += 4) {
            float e;
            e = __expf(dv * A[n  ]); h[n  ] = e * h[n  ] + dub * sX[t*NKX+DTRANK+n  ]; y0 += h[n  ] * sX[t*NKX+DTRANK+DSTATE+n  ];
            e = __expf(dv * A[n+1]); h[n+1] = e * h[n+1] + dub * sX[t*NKX+DTRANK+n+1]; y1 += h[n+1] * sX[t*NKX+DTRANK+DSTATE+n+1];
            e = __expf(dv * A[n+2]); h[n+2] = e * h[n+2] + dub * sX[t*NKX+DTRANK+n+2]; y2 += h[n+2] * sX[t*NKX+DTRANK+DSTATE+n+2];
            e = __expf(dv * A[n+3]); h[n+3] = e * h[n+3] + dub * sX[t*NKX+DTRANK+n+3]; y3 += h[n+3] * sX[t*NKX+DTRANK+DSTATE+n+3];
        }
        const float y = (y0 + y1) + (y2 + y3);
        yl[(size_t)t * DIN] = __float2bfloat16((y + Dd * uv) * silu_f(zz));
    }
}

// ---------------- launcher ----------------
extern "C" void kernel_launch(void* const* d_in, const int* in_sizes, int n_in,
                              void* d_out, int out_size, void* d_ws, size_t ws_size,
                              hipStream_t stream) {
    const float* x      = (const float*)d_in[0];
    const float* W_in   = (const float*)d_in[1];
    const float* conv_w = (const float*)d_in[2];
    const float* conv_b = (const float*)d_in[3];
    const float* W_x    = (const float*)d_in[4];
    const float* W_dt   = (const float*)d_in[5];
    const float* b_dt   = (const float*)d_in[6];
    const float* A_log  = (const float*)d_in[7];
    const float* Dvec   = (const float*)d_in[8];
    const float* W_out  = (const float*)d_in[9];
    float* out = (float*)d_out;

    char* p = (char*)d_ws;
    __hip_bfloat16* xb  = (__hip_bfloat16*)p; p += (size_t)NM * DIMC * 2;     // 6.3MB
    __hip_bfloat16* wbi = (__hip_bfloat16*)p; p += (size_t)NWI * 2;
    __hip_bfloat16* wbo = (__hip_bfloat16*)p; p += (size_t)NWO * 2;
    __hip_bfloat16* wbx = (__hip_bfloat16*)p; p += (size_t)NWX * 2;
    float*          xz  = (float*)p;          p += (size_t)NM * DIN2 * 4;     // 50MB
    __hip_bfloat16* xcb = (__hip_bfloat16*)p; p += (size_t)NM * DIN * 2;      // 12.6MB
    float*          xdbl= (float*)p;          p += (size_t)NM * NKX * 4;      // 2.9MB
    __hip_bfloat16* yb  = (__hip_bfloat16*)p; p += (size_t)NM * DIN * 2;      // 12.6MB
    float*          S   = (float*)p;          p += (size_t)G_CHUNKS * NCH * 4;
    float*          P   = (float*)p;          p += (size_t)G_CHUNKS * NCH * 4;

    // 1. weight + input conversion
    k_cvt_w<<<dim3((NWI + NWO + NWX + 255) / 256), 256, 0, stream>>>(
        W_in, W_out, W_x, wbi, wbo, wbx);
    k_cvt_x<<<dim3(L_SEQ/32, DIMC/32, NB), dim3(32, 8), 0, stream>>>(x, xb);
    // 2. in_proj: xz(m,768) = xb(m,192) @ wbi(768,192)^T
    k_mfma<128, 0><<<dim3(NM/128, DIN2/128), 256, 0, stream>>>(xb, wbi, xz, DIMC, DIN2);
    // 3. depthwise causal conv + silu -> xcb bf16
    k_conv<<<dim3((NM*(size_t)DIN)/256), 256, 0, stream>>>(xz, conv_w, conv_b, xcb);
    // 4. x_proj: xdbl(m,44) = xcb(m,384) @ wbx(64,384)^T   (rows >=44 zero-padded)
    k_mfma<64, 2><<<dim3(NM/128, 1), 256, 0, stream>>>(xcb, wbx, xdbl, DIN, NKX);
    // 5. chunked selective scan (dt_proj inlined)
    k_scan_a<<<dim3(G_CHUNKS, NB), 384, 0, stream>>>(xcb, xdbl, W_dt, b_dt, A_log, S, P);
    k_scan_b<<<dim3(NCH/256), 256, 0, stream>>>(S, P);
    k_scan_c<<<dim3(G_CHUNKS, NB), 384, 0, stream>>>(xcb, xdbl, W_dt, b_dt, A_log,
                                                     S, xz, Dvec, yb);
    // 6. out_proj: out(b,192,l) = yb(m,384) @ wbo(192,384)^T
    k_mfma<64, 1><<<dim3(NM/128, DIMC/64), 256, 0, stream>>>(yb, wbo, out, DIN, 0);
}

// Round 4
// 242.115 us; speedup vs baseline: 1.9762x; 1.2035x over previous
//
#include <hip/hip_runtime.h>
#include <hip/hip_bf16.h>
#include <math.h>

// ---------------- problem constants ----------------
#define L_SEQ 4096            // H*W
#define NB    4
#define DIMC  192
#define DIN   384             // d_inner
#define DIN2  768
#define DTRANK 12
#define DSTATE 16
#define NKX   44              // dt_rank + 2*d_state
#define G_CHUNKS 128
#define T_CHUNK  32           // L_SEQ / G_CHUNKS
#define NCH  (NB*DIN*DSTATE)  // 24576 scan channels
#define NM   (NB*L_SEQ)       // 16384 (b,l) rows
#define NBIG 448              // padded rows of fused x_proj weight (32 BC + 384 dt + pad)

typedef __attribute__((ext_vector_type(8))) short short8;     // 8 bf16 = 4 VGPRs
typedef __attribute__((ext_vector_type(4))) float floatx4;

__device__ __forceinline__ float silu_f(float v) {
    return v / (1.f + __expf(-v));
}
__device__ __forceinline__ float softplus_f(float v) {
    return fmaxf(v, 0.f) + log1pf(__expf(-fabsf(v)));
}

// async global->LDS 16B per lane (wave-uniform base + lane*16 layout)
#define GLOAD_LDS16(g, l)                                                       \
    __builtin_amdgcn_global_load_lds(                                           \
        (const __attribute__((address_space(1))) unsigned int*)(uintptr_t)(g),  \
        (__attribute__((address_space(3))) unsigned int*)(unsigned int)(uintptr_t)(l), \
        16, 0, 0)

// ---------------- convert + transpose x: (b,c,l) f32 -> (b*l, c) bf16 ----------------
__launch_bounds__(256)
__global__ void k_cvt_x(const float* __restrict__ x, __hip_bfloat16* __restrict__ xb) {
    __shared__ float s[32][33];
    const int b = blockIdx.z, c0 = blockIdx.y * 32, l0 = blockIdx.x * 32;
    const int tx = threadIdx.x, ty = threadIdx.y;   // (32, 8)
    const float* xp = x + ((size_t)b * DIMC + c0) * L_SEQ + l0;
#pragma unroll
    for (int r = 0; r < 4; ++r)
        s[ty + r*8][tx] = xp[(size_t)(ty + r*8) * L_SEQ + tx];
    __syncthreads();
    __hip_bfloat16* op = xb + ((size_t)b * L_SEQ + l0) * DIMC + c0;
#pragma unroll
    for (int r = 0; r < 4; ++r) {
        const int lr = ty + r*8;
        op[(size_t)lr * DIMC + tx] = __float2bfloat16(s[tx][lr]);
    }
}

// ------- weights: W_in, W_out -> bf16; build Wbig(448x384) = [Wx[12:44]; Wdt@Wx[:12]; 0] ----
#define NWI (DIN2*DIMC)        // 147456
#define NWO (DIMC*DIN)         // 73728
#define NWBIG (NBIG*DIN)       // 172032
__launch_bounds__(256)
__global__ void k_cvt_w(const float* __restrict__ W_in, const float* __restrict__ W_out,
                        const float* __restrict__ W_x, const float* __restrict__ W_dt,
                        __hip_bfloat16* __restrict__ wbi, __hip_bfloat16* __restrict__ wbo,
                        __hip_bfloat16* __restrict__ wbig) {
    const int i = blockIdx.x * 256 + threadIdx.x;
    if (i < NWI) {
        wbi[i] = __float2bfloat16(W_in[i]);
    } else if (i < NWI + NWO) {
        const int j = i - NWI;
        wbo[j] = __float2bfloat16(W_out[j]);
    } else if (i < NWI + NWO + NWBIG) {
        const int j = i - NWI - NWO;
        const int r = j / DIN, c = j - r * DIN;
        float v;
        if (r < 32) {
            v = W_x[(size_t)(DTRANK + r) * DIN + c];        // B,C rows
        } else if (r < 32 + DIN) {
            const int d = r - 32;                           // composite dt row
            v = 0.f;
#pragma unroll
            for (int q = 0; q < DTRANK; ++q)
                v += W_dt[d * DTRANK + q] * W_x[(size_t)q * DIN + c];
        } else {
            v = 0.f;                                        // pad rows 416..447
        }
        wbig[j] = __float2bfloat16(v);
    }
}

// ---------------- bf16 NT MFMA GEMM ----------------
// C[m][n] = sum_k A[m][k] * B[n][k];  A: (16384 x K) bf16, B: (N x K) bf16.
// BM=128; BN in {64,128}. 256 threads = 4 waves 2x2; wave tile 64 x BN/2.
// OUTMODE 0: bf16 row-major ldc            (in_proj -> xzb)
// OUTMODE 1: f32 at out[b][n][l], m=b*L+l  (out_proj)
// OUTMODE 3: x_proj fused: n<32 -> xbc f32(m,32); 32<=n<416 -> dlt f32(m,384)
//            with dlt = softplus(v + 2*b_dt[n-32])
template<int BN, int OUTMODE>
__launch_bounds__(256)
__global__ void k_mfma(const __hip_bfloat16* __restrict__ A,
                       const __hip_bfloat16* __restrict__ B,
                       float* __restrict__ Cf, __hip_bfloat16* __restrict__ Cb,
                       float* __restrict__ Cf2, const float* __restrict__ bdt,
                       int K, int ldc) {
    constexpr int WN = BN / 2;
    constexpr int TN = WN / 16;
    constexpr int RB = BN / 64;
    __shared__ __align__(16) __hip_bfloat16 sAB[(128 + BN) * 32];
    __hip_bfloat16* sA = sAB;
    __hip_bfloat16* sB = sAB + 128 * 32;

    const int tid = threadIdx.x;
    const int lane = tid & 63;
    const int wave = tid >> 6;
    const int wm = wave >> 1, wn = wave & 1;
    const int m0 = blockIdx.x * 128;
    const int n0 = blockIdx.y * BN;
    const int mlan = lane & 15;
    const int kq = (lane >> 4) * 8;
    const int srow = tid >> 2;
    const int scol = (tid & 3) * 8;

    floatx4 acc[4][TN];
#pragma unroll
    for (int i = 0; i < 4; ++i)
#pragma unroll
        for (int j = 0; j < TN; ++j) acc[i][j] = (floatx4){0.f, 0.f, 0.f, 0.f};

    for (int k0 = 0; k0 < K; k0 += 32) {
        __syncthreads();
#pragma unroll
        for (int r = 0; r < 2; ++r)
            GLOAD_LDS16(&A[(size_t)(m0 + r*64 + srow) * K + k0 + scol],
                        &sA[(size_t)(r*64 + srow) * 32 + scol]);
#pragma unroll
        for (int r = 0; r < RB; ++r)
            GLOAD_LDS16(&B[(size_t)(n0 + r*64 + srow) * K + k0 + scol],
                        &sB[(size_t)(r*64 + srow) * 32 + scol]);
        __syncthreads();

        short8 af[4], bf[TN];
#pragma unroll
        for (int i = 0; i < 4; ++i)
            af[i] = *(const short8*)&sA[(size_t)(wm*64 + i*16 + mlan) * 32 + kq];
#pragma unroll
        for (int j = 0; j < TN; ++j)
            bf[j] = *(const short8*)&sB[(size_t)(wn*WN + j*16 + mlan) * 32 + kq];
#pragma unroll
        for (int i = 0; i < 4; ++i)
#pragma unroll
            for (int j = 0; j < TN; ++j)
                acc[i][j] = __builtin_amdgcn_mfma_f32_16x16x32_bf16(
                    af[i], bf[j], acc[i][j], 0, 0, 0);
    }

    const int quad = lane >> 4;
#pragma unroll
    for (int i = 0; i < 4; ++i) {
#pragma unroll
        for (int j = 0; j < TN; ++j) {
            const int n = n0 + wn*WN + j*16 + mlan;
            const int mb = m0 + wm*64 + i*16 + quad*4;
#pragma unroll
            for (int r = 0; r < 4; ++r) {
                const int m = mb + r;
                const float v = acc[i][j][r];
                if (OUTMODE == 0) {
                    Cb[(size_t)m * ldc + n] = __float2bfloat16(v);
                } else if (OUTMODE == 1) {
                    const int bb = m >> 12, ll = m & (L_SEQ - 1);
                    Cf[((size_t)bb * DIMC + n) * L_SEQ + ll] = v;
                } else {
                    if (n < 32) {
                        Cf[(size_t)m * 32 + n] = v;
                    } else if (n < 32 + DIN) {
                        const int d = n - 32;
                        Cf2[(size_t)m * DIN + d] = softplus_f(v + 2.f * bdt[d]);
                    }
                }
            }
        }
    }
}

// ---------------- depthwise causal conv4 + SiLU: xzb bf16 (stride 768) -> bf16 -----
__launch_bounds__(256)
__global__ void k_conv(const __hip_bfloat16* __restrict__ xz, const float* __restrict__ cw,
                       const float* __restrict__ cb, __hip_bfloat16* __restrict__ xcb) {
    const int idx = blockIdx.x * 256 + threadIdx.x;   // m*DIN + d
    const int d = idx % DIN;
    const int m = idx / DIN;
    const int l = m & (L_SEQ - 1);
    const float4 w4 = *(const float4*)&cw[d * 4];
    float s = cb[d];
    const float w[4] = {w4.x, w4.y, w4.z, w4.w};
#pragma unroll
    for (int k = 0; k < 4; ++k) {
        const int ll = l - 3 + k;
        if (ll >= 0) s += __bfloat162float(xz[(size_t)(m - 3 + k) * DIN2 + d]) * w[k];
    }
    xcb[idx] = __float2bfloat16(silu_f(s));
}

// ---------------- scan phase a: per-chunk partial state + chunk product -----------
// 768 threads: d = tid>>1, half = tid&1 owns 8 state lanes. dlt precomputed.
__launch_bounds__(768, 6)
__global__ void k_scan_a(const float* __restrict__ dlt, const __hip_bfloat16* __restrict__ xcb,
                         const float* __restrict__ xbc, const float* __restrict__ A_log,
                         float* __restrict__ S, float* __restrict__ P) {
    __shared__ float sBC[T_CHUNK * 32];
    const int tid = threadIdx.x;
    const int g = blockIdx.x, b = blockIdx.y;
    const size_t row0 = (size_t)b * L_SEQ + g * T_CHUNK;
    for (int i = tid; i < T_CHUNK * 32; i += 768)
        sBC[i] = xbc[row0 * 32 + i];
    __syncthreads();
    const int d = tid >> 1, half = tid & 1;
    const int nb = half * 8;
    float A[8];
#pragma unroll
    for (int j = 0; j < 8; ++j) A[j] = -__expf(A_log[d * DSTATE + nb + j]);
    float h[8] = {};
    float dsum = 0.f;
    const float* dl = dlt + row0 * DIN + d;
    const __hip_bfloat16* ul = xcb + row0 * DIN + d;
    for (int t = 0; t < T_CHUNK; ++t) {
        const float dv = dl[(size_t)t * DIN];
        const float uv = __bfloat162float(ul[(size_t)t * DIN]);
        const float dub = dv * uv;
        dsum += dv;
#pragma unroll
        for (int j = 0; j < 8; ++j) {
            const float e = __expf(dv * A[j]);
            h[j] = e * h[j] + dub * sBC[t*32 + nb + j];
        }
    }
    float* Sp = S + (size_t)g * NCH + (size_t)(b * DIN + d) * DSTATE + nb;
    float* Pp = P + (size_t)g * NCH + (size_t)(b * DIN + d) * DSTATE + nb;
    *(float4*)&Sp[0] = make_float4(h[0], h[1], h[2], h[3]);
    *(float4*)&Sp[4] = make_float4(h[4], h[5], h[6], h[7]);
    *(float4*)&Pp[0] = make_float4(__expf(A[0]*dsum), __expf(A[1]*dsum),
                                   __expf(A[2]*dsum), __expf(A[3]*dsum));
    *(float4*)&Pp[4] = make_float4(__expf(A[4]*dsum), __expf(A[5]*dsum),
                                   __expf(A[6]*dsum), __expf(A[7]*dsum));
}

// ---------------- scan phase b: sequential combine; S becomes entering state ------
__launch_bounds__(256)
__global__ void k_scan_b(float* __restrict__ Sh, const float* __restrict__ P) {
    const int ch = blockIdx.x * 256 + threadIdx.x;
    float h = 0.f;
    for (int g = 0; g < G_CHUNKS; ++g) {
        const size_t i = (size_t)g * NCH + ch;
        const float s = Sh[i];
        const float p = P[i];
        Sh[i] = h;
        h = p * h + s;
    }
}

// ---------------- scan phase c: replay + y + D*u + gate -> yb bf16 ----------------
__launch_bounds__(768, 6)
__global__ void k_scan_c(const float* __restrict__ dlt, const __hip_bfloat16* __restrict__ xcb,
                         const float* __restrict__ xbc, const float* __restrict__ A_log,
                         const float* __restrict__ Hst, const __hip_bfloat16* __restrict__ xzb,
                         const float* __restrict__ Dv, __hip_bfloat16* __restrict__ yb) {
    __shared__ float sBC[T_CHUNK * 32];
    const int tid = threadIdx.x;
    const int g = blockIdx.x, b = blockIdx.y;
    const size_t row0 = (size_t)b * L_SEQ + g * T_CHUNK;
    for (int i = tid; i < T_CHUNK * 32; i += 768)
        sBC[i] = xbc[row0 * 32 + i];
    __syncthreads();
    const int d = tid >> 1, half = tid & 1;
    const int nb = half * 8;
    float A[8];
#pragma unroll
    for (int j = 0; j < 8; ++j) A[j] = -__expf(A_log[d * DSTATE + nb + j]);
    float h[8];
    const float* Hp = Hst + (size_t)g * NCH + (size_t)(b * DIN + d) * DSTATE + nb;
    {
        const float4 h0 = *(const float4*)&Hp[0];
        const float4 h1 = *(const float4*)&Hp[4];
        h[0]=h0.x; h[1]=h0.y; h[2]=h0.z; h[3]=h0.w;
        h[4]=h1.x; h[5]=h1.y; h[6]=h1.z; h[7]=h1.w;
    }
    const float Dd = Dv[d];
    const float* dl = dlt + row0 * DIN + d;
    const __hip_bfloat16* ul = xcb + row0 * DIN + d;
    const __hip_bfloat16* zl = xzb + row0 * DIN2 + DIN + d;
    __hip_bfloat16* yl = yb + row0 * DIN + d;
    for (int t = 0; t < T_CHUNK; ++t) {
        const float dv = dl[(size_t)t * DIN];
        const float uv = __bfloat162float(ul[(size_t)t * DIN]);
        const float dub = dv * uv;
        float y = 0.f;
#pragma unroll
        for (int j = 0; j < 8; ++j) {
            const float e = __expf(dv * A[j]);
            h[j] = e * h[j] + dub * sBC[t*32 + nb + j];
            y += h[j] * sBC[t*32 + 16 + nb + j];
        }
        y += __shfl_xor(y, 1);                    // combine the two halves
        if (half == 0) {
            const float zz = __bfloat162float(zl[(size_t)t * DIN2]);
            yl[(size_t)t * DIN] = __float2bfloat16((y + Dd * uv) * silu_f(zz));
        }
    }
}

// ---------------- launcher ----------------
extern "C" void kernel_launch(void* const* d_in, const int* in_sizes, int n_in,
                              void* d_out, int out_size, void* d_ws, size_t ws_size,
                              hipStream_t stream) {
    const float* x      = (const float*)d_in[0];
    const float* W_in   = (const float*)d_in[1];
    const float* conv_w = (const float*)d_in[2];
    const float* conv_b = (const float*)d_in[3];
    const float* W_x    = (const float*)d_in[4];
    const float* W_dt   = (const float*)d_in[5];
    const float* b_dt   = (const float*)d_in[6];
    const float* A_log  = (const float*)d_in[7];
    const float* Dvec   = (const float*)d_in[8];
    const float* W_out  = (const float*)d_in[9];
    float* out = (float*)d_out;

    char* p = (char*)d_ws;
    __hip_bfloat16* xb   = (__hip_bfloat16*)p; p += (size_t)NM * DIMC * 2;
    __hip_bfloat16* wbi  = (__hip_bfloat16*)p; p += (size_t)NWI * 2;
    __hip_bfloat16* wbo  = (__hip_bfloat16*)p; p += (size_t)NWO * 2;
    __hip_bfloat16* wbig = (__hip_bfloat16*)p; p += (size_t)NWBIG * 2;
    __hip_bfloat16* xzb  = (__hip_bfloat16*)p; p += (size_t)NM * DIN2 * 2;    // 25MB
    __hip_bfloat16* xcb  = (__hip_bfloat16*)p; p += (size_t)NM * DIN * 2;     // 12.6MB
    float*          xbc  = (float*)p;          p += (size_t)NM * 32 * 4;      // 2.1MB
    float*          dlt  = (float*)p;          p += (size_t)NM * DIN * 4;     // 25MB
    __hip_bfloat16* yb   = (__hip_bfloat16*)p; p += (size_t)NM * DIN * 2;     // 12.6MB
    float*          S    = (float*)p;          p += (size_t)G_CHUNKS * NCH * 4;
    float*          P    = (float*)p;          p += (size_t)G_CHUNKS * NCH * 4;

    // 1. weight conversion + composite dt weight; input transpose+convert
    k_cvt_w<<<dim3((NWI + NWO + NWBIG + 255) / 256), 256, 0, stream>>>(
        W_in, W_out, W_x, W_dt, wbi, wbo, wbig);
    k_cvt_x<<<dim3(L_SEQ/32, DIMC/32, NB), dim3(32, 8), 0, stream>>>(x, xb);
    // 2. in_proj: xzb(m,768) bf16 = xb(m,192) @ wbi(768,192)^T
    k_mfma<128, 0><<<dim3(NM/128, DIN2/128), 256, 0, stream>>>(
        xb, wbi, nullptr, xzb, nullptr, nullptr, DIMC, DIN2);
    // 3. depthwise causal conv + silu -> xcb bf16
    k_conv<<<dim3((NM*(size_t)DIN)/256), 256, 0, stream>>>(xzb, conv_w, conv_b, xcb);
    // 4. fused x_proj + dt_proj: xbc(m,32) f32, dlt(m,384)=softplus f32
    k_mfma<64, 3><<<dim3(NM/128, NBIG/64), 256, 0, stream>>>(
        xcb, wbig, xbc, nullptr, dlt, b_dt, DIN, 0);
    // 5. chunked selective scan
    k_scan_a<<<dim3(G_CHUNKS, NB), 768, 0, stream>>>(dlt, xcb, xbc, A_log, S, P);
    k_scan_b<<<dim3(NCH/256), 256, 0, stream>>>(S, P);
    k_scan_c<<<dim3(G_CHUNKS, NB), 768, 0, stream>>>(dlt, xcb, xbc, A_log, S, xzb, Dvec, yb);
    // 6. out_proj: out(b,192,l) = yb(m,384) @ wbo(192,384)^T
    k_mfma<64, 1><<<dim3(NM/128, DIMC/64), 256, 0, stream>>>(
        yb, wbo, out, nullptr, nullptr, nullptr, DIN, 0);
}